// Round 7
// baseline (1310.919 us; speedup 1.0000x reference)
//
#include <hip/hip_runtime.h>
#include <math.h>

#define THREADS 256

// ---- v2 (two-level, coalesced-write) parameters ----
#define SHC 7                // col-group width 128 nodes
#define GWC 128
#define SHR 11               // row-group width 2048 nodes
#define GWR 2048
#define MAXGC 1600           // max col groups (N <= 204800)
#define MAXGR 128            // max row groups
#define CHUNK2 131072        // edges per level-1 block
#define P2CAP 12288          // place2 LDS capacity (entries per col group)

// ---- round-6 fallback parameters ----
#define SH 7
#define BINW 128
#define MAXBIN 2048
#define CHUNK 8192
#define K4CAP 12288
#define SLOTU 50000

// ======================= v2: level-1 hist / scan / scatter =======================

__global__ void hist2_kernel(const int* __restrict__ row, const int* __restrict__ col,
                             int* __restrict__ D2c, int* __restrict__ D2r,
                             int E, int NG, int NGR) {
    __shared__ int hc[MAXGC], hr[MAXGR];
    for (int i = threadIdx.x; i < NG; i += THREADS) hc[i] = 0;
    for (int i = threadIdx.x; i < NGR; i += THREADS) hr[i] = 0;
    __syncthreads();
    int base = blockIdx.x * CHUNK2;
    int lim = min(CHUNK2, E - base);
    for (int k = threadIdx.x; k < lim; k += THREADS) {
        int e = base + k;
        atomicAdd(&hc[col[e] >> SHC], 1);
        atomicAdd(&hr[row[e] >> SHR], 1);
    }
    __syncthreads();
    for (int i = threadIdx.x; i < NG; i += THREADS) D2c[(size_t)blockIdx.x * NG + i] = hc[i];
    for (int i = threadIdx.x; i < NGR; i += THREADS) D2r[(size_t)blockIdx.x * NGR + i] = hr[i];
}

__global__ void scan_col_kernel(int* __restrict__ D, int* __restrict__ binTot,
                                int NBLK, int NBIN) {
    __shared__ int tmp[THREADS];
    int b = blockIdx.x;
    int carry = 0;
    for (int base = 0; base < NBLK; base += THREADS) {
        int idx = base + threadIdx.x;
        int v = (idx < NBLK) ? D[(size_t)idx * NBIN + b] : 0;
        tmp[threadIdx.x] = v;
        __syncthreads();
        for (int d = 1; d < THREADS; d <<= 1) {
            int u = (threadIdx.x >= d) ? tmp[threadIdx.x - d] : 0;
            __syncthreads();
            tmp[threadIdx.x] += u;
            __syncthreads();
        }
        if (idx < NBLK) D[(size_t)idx * NBIN + b] = carry + tmp[threadIdx.x] - v;
        carry += tmp[THREADS - 1];
        __syncthreads();
    }
    if (threadIdx.x == 0) binTot[b] = carry;
}

__global__ void scan_bins_kernel(const int* __restrict__ binTot, int* __restrict__ binBase, int NBIN) {
    __shared__ int tmp[1024];
    int carry = 0;
    for (int base = 0; base < NBIN; base += 1024) {
        int i = base + threadIdx.x;
        int v = (i < NBIN) ? binTot[i] : 0;
        tmp[threadIdx.x] = v;
        __syncthreads();
        for (int d = 1; d < 1024; d <<= 1) {
            int u = (threadIdx.x >= d) ? tmp[threadIdx.x - d] : 0;
            __syncthreads();
            tmp[threadIdx.x] += u;
            __syncthreads();
        }
        if (i < NBIN) binBase[i] = carry + tmp[threadIdx.x] - v;
        carry += tmp[1023];
        __syncthreads();
    }
    if (threadIdx.x == 0) binBase[NBIN] = carry;
}

__global__ void add_base_kernel(int* __restrict__ D, const int* __restrict__ binBase,
                                int NBLK, int NBIN) {
    size_t i = (size_t)blockIdx.x * blockDim.x + threadIdx.x;
    if (i < (size_t)NBLK * NBIN) D[i] += binBase[i % NBIN];
}

// level-1 scatter: A1 = col-grouped packed (r | c_low<<18), B1 = row-grouped r_low (u16)
__global__ void scatter2_kernel(const int* __restrict__ row, const int* __restrict__ col,
                                const int* __restrict__ D2c, const int* __restrict__ D2r,
                                unsigned int* __restrict__ A1, unsigned short* __restrict__ B1,
                                int E, int NG, int NGR) {
    __shared__ int lc[MAXGC], lr[MAXGR];
    for (int i = threadIdx.x; i < NG; i += THREADS) lc[i] = D2c[(size_t)blockIdx.x * NG + i];
    for (int i = threadIdx.x; i < NGR; i += THREADS) lr[i] = D2r[(size_t)blockIdx.x * NGR + i];
    __syncthreads();
    int base = blockIdx.x * CHUNK2;
    int lim = min(CHUNK2, E - base);
    for (int k = threadIdx.x; k < lim; k += THREADS) {
        int e = base + k;
        int c = col[e], r = row[e];
        int pc = atomicAdd(&lc[c >> SHC], 1);
        A1[pc] = (unsigned int)r | ((unsigned int)(c & (GWC - 1)) << 18);
        int pr = atomicAdd(&lr[r >> SHR], 1);
        B1[pr] = (unsigned short)(r & (GWR - 1));
    }
}

// per row-group degree histogram -> dis
__global__ void deg2_kernel(const unsigned short* __restrict__ B1,
                            const int* __restrict__ basR,
                            float* __restrict__ dis, int N) {
    __shared__ int cnt[GWR];
    int b = blockIdx.x;
    for (int i = threadIdx.x; i < GWR; i += THREADS) cnt[i] = 0;
    __syncthreads();
    int p0 = basR[b], p1 = basR[b + 1];
    for (int i = p0 + threadIdx.x; i < p1; i += THREADS)
        atomicAdd(&cnt[B1[i]], 1);
    __syncthreads();
    for (int i = threadIdx.x; i < GWR; i += THREADS) {
        int node = (b << SHR) + i;
        if (node < N) {
            int c = cnt[i];
            dis[node] = c > 0 ? rsqrtf((float)c) : 0.f;
        }
    }
}

// per col-group: stage -> count -> scan -> permute in LDS -> coalesced dump to A
__global__ void place2_kernel(const unsigned int* __restrict__ A1,
                              const int* __restrict__ basC,
                              int* __restrict__ off, int* __restrict__ A, int N) {
    __shared__ unsigned int bufin[P2CAP], bufout[P2CAP];
    __shared__ int cnt[GWC], pref[GWC], tmpv[GWC];
    int b = blockIdx.x;
    int t = threadIdx.x;
    int p0 = basC[b], p1 = basC[b + 1];
    int sz = p1 - p0;
    if (t < GWC) cnt[t] = 0;
    __syncthreads();
    if (sz <= P2CAP) {
        for (int i = t; i < sz; i += THREADS) {
            unsigned int a = A1[p0 + i];
            bufin[i] = a;
            atomicAdd(&cnt[(a >> 18) & (GWC - 1)], 1);
        }
        __syncthreads();
        int v = (t < GWC) ? cnt[t] : 0;
        if (t < GWC) tmpv[t] = v;
        __syncthreads();
        for (int d = 1; d < GWC; d <<= 1) {
            int u = (t >= d && t < GWC) ? tmpv[t - d] : 0;
            __syncthreads();
            if (t < GWC) tmpv[t] += u;
            __syncthreads();
        }
        if (t < GWC) {
            pref[t] = tmpv[t] - v;
            int node = (b << SHC) + t;
            if (node < N) off[node] = p0 + pref[t];
        }
        __syncthreads();
        for (int i = t; i < sz; i += THREADS) {
            unsigned int a = bufin[i];
            int cl = (a >> 18) & (GWC - 1);
            int p = atomicAdd(&pref[cl], 1);
            bufout[p] = a & 0x3FFFFu;
        }
        __syncthreads();
        for (int i = t; i < sz; i += THREADS) A[p0 + i] = (int)bufout[i];
    } else {
        // rare oversized group: two global passes, direct writes (A != A1, safe)
        for (int i = t; i < sz; i += THREADS)
            atomicAdd(&cnt[(A1[p0 + i] >> 18) & (GWC - 1)], 1);
        __syncthreads();
        int v = (t < GWC) ? cnt[t] : 0;
        if (t < GWC) tmpv[t] = v;
        __syncthreads();
        for (int d = 1; d < GWC; d <<= 1) {
            int u = (t >= d && t < GWC) ? tmpv[t - d] : 0;
            __syncthreads();
            if (t < GWC) tmpv[t] += u;
            __syncthreads();
        }
        if (t < GWC) {
            pref[t] = tmpv[t] - v;
            int node = (b << SHC) + t;
            if (node < N) off[node] = p0 + pref[t];
        }
        __syncthreads();
        for (int i = t; i < sz; i += THREADS) {
            unsigned int a = A1[p0 + i];
            int cl = (a >> 18) & (GWC - 1);
            int p = atomicAdd(&pref[cl], 1);
            A[p0 + p] = (int)(a & 0x3FFFFu);
        }
    }
}

// ======================= 4-lane cooperative fused gather + dense =======================

__global__ void gather_dense1_w4(const int* __restrict__ off, const int* __restrict__ csr_src,
                                 const float* __restrict__ dis, const float* __restrict__ x,
                                 const float* __restrict__ W0, const float* __restrict__ W1,
                                 const float* __restrict__ b, float* __restrict__ h1,
                                 int N, int E) {
    __shared__ float sW0[128], sW1[128], sb[16];
    for (int i = threadIdx.x; i < 128; i += blockDim.x) { sW0[i] = W0[i]; sW1[i] = W1[i]; }
    if (threadIdx.x < 16) sb[threadIdx.x] = b[threadIdx.x];
    __syncthreads();
    int t = blockIdx.x * blockDim.x + threadIdx.x;
    int g = t >> 2, sub = t & 3;
    if (g >= N) return;
    int p0 = __builtin_nontemporal_load(&off[g]);
    int p1 = (g == N - 1) ? E : __builtin_nontemporal_load(&off[g + 1]);
    float tx[8] = {0, 0, 0, 0, 0, 0, 0, 0};
    for (int p = p0 + sub; p < p1; p += 4) {
        int src = __builtin_nontemporal_load(&csr_src[p]);
        float wv = dis[src];
        const float4* fr = reinterpret_cast<const float4*>(x + (size_t)src * 8);
        float4 a = fr[0], bb = fr[1];
        tx[0] += wv * a.x;  tx[1] += wv * a.y;  tx[2] += wv * a.z;  tx[3] += wv * a.w;
        tx[4] += wv * bb.x; tx[5] += wv * bb.y; tx[6] += wv * bb.z; tx[7] += wv * bb.w;
    }
#pragma unroll
    for (int i = 0; i < 8; ++i) {
        tx[i] += __shfl_xor(tx[i], 1);
        tx[i] += __shfl_xor(tx[i], 2);
    }
    float xa[8];
    const float4* xr = reinterpret_cast<const float4*>(x + (size_t)g * 8);
    float4 a = xr[0], bb = xr[1];
    xa[0] = a.x; xa[1] = a.y; xa[2] = a.z; xa[3] = a.w;
    xa[4] = bb.x; xa[5] = bb.y; xa[6] = bb.z; xa[7] = bb.w;
    float sc = -dis[g];
    int ob = sub * 4;
    float acc[4];
#pragma unroll
    for (int j = 0; j < 4; ++j) acc[j] = sb[ob + j];
#pragma unroll
    for (int f = 0; f < 8; ++f) {
        float xv = xa[f], tv = sc * tx[f];
#pragma unroll
        for (int j = 0; j < 4; ++j) acc[j] += xv * sW0[f * 16 + ob + j] + tv * sW1[f * 16 + ob + j];
    }
    float4 q;
    q.x = fmaxf(acc[0], 0.f); q.y = fmaxf(acc[1], 0.f);
    q.z = fmaxf(acc[2], 0.f); q.w = fmaxf(acc[3], 0.f);
    reinterpret_cast<float4*>(h1 + (size_t)g * 16)[sub] = q;
}

__global__ void gather_dense2_w4(const int* __restrict__ off, const int* __restrict__ csr_src,
                                 const float* __restrict__ dis, const float* __restrict__ h1,
                                 const float* __restrict__ W0, const float* __restrict__ W1,
                                 const float* __restrict__ b, const float* __restrict__ Wr,
                                 const float* __restrict__ br, float* __restrict__ s,
                                 int N, int E) {
    __shared__ float sW0[256], sW1[256], sb[16], sWr[16], sbr;
    for (int i = threadIdx.x; i < 256; i += blockDim.x) { sW0[i] = W0[i]; sW1[i] = W1[i]; }
    if (threadIdx.x < 16) { sb[threadIdx.x] = b[threadIdx.x]; sWr[threadIdx.x] = Wr[threadIdx.x]; }
    if (threadIdx.x == 0) sbr = br[0];
    __syncthreads();
    int t = blockIdx.x * blockDim.x + threadIdx.x;
    int g = t >> 2, sub = t & 3;
    if (g >= N) return;
    int p0 = __builtin_nontemporal_load(&off[g]);
    int p1 = (g == N - 1) ? E : __builtin_nontemporal_load(&off[g + 1]);
    float tx[16];
#pragma unroll
    for (int o = 0; o < 16; ++o) tx[o] = 0.f;
    for (int p = p0 + sub; p < p1; p += 4) {
        int src = __builtin_nontemporal_load(&csr_src[p]);
        float wv = dis[src];
        const float4* fr = reinterpret_cast<const float4*>(h1 + (size_t)src * 16);
#pragma unroll
        for (int v = 0; v < 4; ++v) {
            float4 q = fr[v];
            tx[v * 4 + 0] += wv * q.x;
            tx[v * 4 + 1] += wv * q.y;
            tx[v * 4 + 2] += wv * q.z;
            tx[v * 4 + 3] += wv * q.w;
        }
    }
#pragma unroll
    for (int i = 0; i < 16; ++i) {
        tx[i] += __shfl_xor(tx[i], 1);
        tx[i] += __shfl_xor(tx[i], 2);
    }
    float ha[16];
    const float4* hr = reinterpret_cast<const float4*>(h1 + (size_t)g * 16);
#pragma unroll
    for (int v = 0; v < 4; ++v) {
        float4 q = hr[v];
        ha[v * 4 + 0] = q.x; ha[v * 4 + 1] = q.y; ha[v * 4 + 2] = q.z; ha[v * 4 + 3] = q.w;
    }
    float sc = -dis[g];
    int ob = sub * 4;
    float acc[4];
#pragma unroll
    for (int j = 0; j < 4; ++j) acc[j] = sb[ob + j];
#pragma unroll
    for (int f = 0; f < 16; ++f) {
        float hv = ha[f], tv = sc * tx[f];
#pragma unroll
        for (int j = 0; j < 4; ++j) acc[j] += hv * sW0[f * 16 + ob + j] + tv * sW1[f * 16 + ob + j];
    }
    float sv = 0.f;
#pragma unroll
    for (int j = 0; j < 4; ++j) sv += fmaxf(acc[j], 0.f) * sWr[ob + j];
    sv += __shfl_xor(sv, 1);
    sv += __shfl_xor(sv, 2);
    if (sub == 0) s[g] = sv + sbr;
}

__global__ void softmax_kernel(const float* __restrict__ s, const int* __restrict__ batch,
                               float* __restrict__ out, int N) {
    int g = blockIdx.x;
    __shared__ float red[THREADS];
    int lo, hi;
    { int a = 0, b = N; while (a < b) { int mid = (a + b) >> 1; if (batch[mid] < g) a = mid + 1; else b = mid; } lo = a; }
    { int a = lo, b = N; while (a < b) { int mid = (a + b) >> 1; if (batch[mid] < g + 1) a = mid + 1; else b = mid; } hi = a; }
    float mx = -INFINITY;
    for (int i = lo + threadIdx.x; i < hi; i += THREADS) mx = fmaxf(mx, s[i]);
    red[threadIdx.x] = mx;
    __syncthreads();
    for (int d = THREADS / 2; d > 0; d >>= 1) {
        if (threadIdx.x < d) red[threadIdx.x] = fmaxf(red[threadIdx.x], red[threadIdx.x + d]);
        __syncthreads();
    }
    mx = red[0];
    __syncthreads();
    float sum = 0.f;
    for (int i = lo + threadIdx.x; i < hi; i += THREADS) sum += expf(s[i] - mx);
    red[threadIdx.x] = sum;
    __syncthreads();
    for (int d = THREADS / 2; d > 0; d >>= 1) {
        if (threadIdx.x < d) red[threadIdx.x] += red[threadIdx.x + d];
        __syncthreads();
    }
    float inv = 1.f / red[0];
    for (int i = lo + threadIdx.x; i < hi; i += THREADS) out[i] = expf(s[i] - mx) * inv;
}

// ======================= round-6 fallback kernels =======================

__global__ void hist_kernel(const int* __restrict__ row, const int* __restrict__ col,
                            int* __restrict__ Dcol, int* __restrict__ Drow,
                            int E, int NBIN) {
    __shared__ int hc[MAXBIN], hr[MAXBIN];
    for (int i = threadIdx.x; i < NBIN; i += THREADS) { hc[i] = 0; hr[i] = 0; }
    __syncthreads();
    int base = blockIdx.x * CHUNK;
#pragma unroll
    for (int k = 0; k < CHUNK / THREADS; ++k) {
        int e = base + k * THREADS + threadIdx.x;
        if (e < E) {
            atomicAdd(&hc[col[e] >> SH], 1);
            atomicAdd(&hr[row[e] >> SH], 1);
        }
    }
    __syncthreads();
    size_t ob = (size_t)blockIdx.x * NBIN;
    for (int i = threadIdx.x; i < NBIN; i += THREADS) {
        Dcol[ob + i] = hc[i];
        Drow[ob + i] = hr[i];
    }
}

__global__ void scatter_kernel(const int* __restrict__ row, const int* __restrict__ col,
                               const int* __restrict__ Dcol, const int* __restrict__ Drow,
                               unsigned int* __restrict__ A, unsigned char* __restrict__ Cu8,
                               int E, int NBIN) {
    __shared__ int lc[MAXBIN], lr[MAXBIN];
    size_t ob = (size_t)blockIdx.x * NBIN;
    for (int i = threadIdx.x; i < NBIN; i += THREADS) { lc[i] = Dcol[ob + i]; lr[i] = Drow[ob + i]; }
    __syncthreads();
    int base = blockIdx.x * CHUNK;
#pragma unroll
    for (int k = 0; k < CHUNK / THREADS; ++k) {
        int e = base + k * THREADS + threadIdx.x;
        if (e < E) {
            int c = col[e], r = row[e];
            int pc = atomicAdd(&lc[c >> SH], 1);
            A[pc] = (unsigned int)r | ((unsigned int)(c & (BINW - 1)) << 18);
            int pr = atomicAdd(&lr[r >> SH], 1);
            Cu8[pr] = (unsigned char)(r & (BINW - 1));
        }
    }
}

__global__ void deg_bins_kernel(const unsigned char* __restrict__ Cu8,
                                const int* __restrict__ binBaseR,
                                float* __restrict__ dis, int N) {
    __shared__ int cnt[BINW];
    int b = blockIdx.x;
    if (threadIdx.x < BINW) cnt[threadIdx.x] = 0;
    __syncthreads();
    int p0 = binBaseR[b], p1 = binBaseR[b + 1];
    for (int i = p0 + threadIdx.x; i < p1; i += THREADS)
        atomicAdd(&cnt[Cu8[i]], 1);
    __syncthreads();
    int node = (b << SH) + threadIdx.x;
    if (threadIdx.x < BINW && node < N) {
        int c = cnt[threadIdx.x];
        dis[node] = c > 0 ? rsqrtf((float)c) : 0.f;
    }
}

__global__ void csr_place_kernel(unsigned int* __restrict__ A,
                                 const int* __restrict__ binBaseC,
                                 int* __restrict__ off,
                                 unsigned int* __restrict__ scratch,
                                 int N) {
    __shared__ unsigned int buf[K4CAP];
    __shared__ int cnt[BINW], pref[BINW], tmp[BINW];
    int b = blockIdx.x;
    int t = threadIdx.x;
    int p0 = binBaseC[b], p1 = binBaseC[b + 1];
    int sz = p1 - p0;
    const unsigned int* src;
    if (sz <= K4CAP) {
        for (int i = t; i < sz; i += THREADS) buf[i] = A[p0 + i];
        src = buf;
    } else {
        unsigned int* sc = scratch + (size_t)(b & 63) * SLOTU;
        for (int i = t; i < sz && i < SLOTU; i += THREADS) sc[i] = A[p0 + i];
        src = sc;
    }
    if (t < BINW) cnt[t] = 0;
    __syncthreads();
    for (int i = t; i < sz; i += THREADS)
        atomicAdd(&cnt[(src[i] >> 18) & (BINW - 1)], 1);
    __syncthreads();
    int v = (t < BINW) ? cnt[t] : 0;
    if (t < BINW) tmp[t] = v;
    __syncthreads();
    for (int d = 1; d < BINW; d <<= 1) {
        int u = (t >= d && t < BINW) ? tmp[t - d] : 0;
        __syncthreads();
        if (t < BINW) tmp[t] += u;
        __syncthreads();
    }
    if (t < BINW) pref[t] = tmp[t] - v;
    int node = (b << SH) + t;
    if (t < BINW && node < N) off[node] = p0 + pref[t];
    __syncthreads();
    for (int i = t; i < sz; i += THREADS) {
        unsigned int a = src[i];
        int cl = (a >> 18) & (BINW - 1);
        int p = atomicAdd(&pref[cl], 1);
        A[(size_t)p0 + p] = a & 0x3FFFFu;
    }
}

// ======================= round-2 final fallback =======================

__global__ void deg_cnt_kernel(const int* __restrict__ row, const int* __restrict__ col,
                               int* __restrict__ deg_i, int* __restrict__ cnt, int E) {
    int e = blockIdx.x * blockDim.x + threadIdx.x;
    if (e >= E) return;
    atomicAdd(&deg_i[row[e]], 1);
    atomicAdd(&cnt[col[e]], 1);
}

__global__ void dis_kernel_i(const int* __restrict__ deg_i, float* __restrict__ dis, int N) {
    int i = blockIdx.x * blockDim.x + threadIdx.x;
    if (i < N) {
        int d = deg_i[i];
        dis[i] = d > 0 ? rsqrtf((float)d) : 0.f;
    }
}

__global__ void scan1_kernel(const int* __restrict__ cnt, int* __restrict__ off,
                             int* __restrict__ bsum, int n) {
    __shared__ int tmp[THREADS];
    int i = blockIdx.x * THREADS + threadIdx.x;
    int v = (i < n) ? cnt[i] : 0;
    tmp[threadIdx.x] = v;
    __syncthreads();
    for (int d = 1; d < THREADS; d <<= 1) {
        int t = (threadIdx.x >= d) ? tmp[threadIdx.x - d] : 0;
        __syncthreads();
        tmp[threadIdx.x] += t;
        __syncthreads();
    }
    if (i < n) off[i] = tmp[threadIdx.x] - v;
    if (threadIdx.x == THREADS - 1) bsum[blockIdx.x] = tmp[threadIdx.x];
}

__global__ void scan2_kernel(int* __restrict__ bsum, int nb) {
    __shared__ int tmp[1024];
    int carry = 0;
    for (int base = 0; base < nb; base += 1024) {
        int i = base + threadIdx.x;
        int v = (i < nb) ? bsum[i] : 0;
        tmp[threadIdx.x] = v;
        __syncthreads();
        for (int d = 1; d < 1024; d <<= 1) {
            int t = (threadIdx.x >= d) ? tmp[threadIdx.x - d] : 0;
            __syncthreads();
            tmp[threadIdx.x] += t;
            __syncthreads();
        }
        if (i < nb) bsum[i] = carry + tmp[threadIdx.x] - v;
        carry += tmp[1023];
        __syncthreads();
    }
}

__global__ void scan3_kernel(int* __restrict__ off, const int* __restrict__ bsum, int n) {
    int i = blockIdx.x * THREADS + threadIdx.x;
    if (i < n) off[i] += bsum[blockIdx.x];
}

__global__ void fill_csr_kernel(const int* __restrict__ row, const int* __restrict__ col,
                                const int* __restrict__ off, int* __restrict__ fill,
                                int* __restrict__ csr_src, int E) {
    int e = blockIdx.x * blockDim.x + threadIdx.x;
    if (e >= E) return;
    int c = col[e];
    int p = off[c] + atomicAdd(&fill[c], 1);
    csr_src[p] = row[e];
}

// ======================= launch =======================

extern "C" void kernel_launch(void* const* d_in, const int* in_sizes, int n_in,
                              void* d_out, int out_size, void* d_ws, size_t ws_size,
                              hipStream_t stream) {
    const float* x     = (const float*)d_in[0];
    const int*   ei    = (const int*)d_in[1];
    const int*   batch = (const int*)d_in[2];
    const float* W1_0  = (const float*)d_in[3];
    const float* W1_1  = (const float*)d_in[4];
    const float* b1    = (const float*)d_in[5];
    const float* W2_0  = (const float*)d_in[6];
    const float* W2_1  = (const float*)d_in[7];
    const float* b2    = (const float*)d_in[8];
    const float* Wr    = (const float*)d_in[9];
    const float* br    = (const float*)d_in[10];
    float* out = (float*)d_out;

    const int N = in_sizes[2];
    const int E = in_sizes[1] / 2;
    const int G = 256;
    const int* row = ei;
    const int* col = ei + E;

    const int gN = (N + THREADS - 1) / THREADS;
    const int gE = (E + THREADS - 1) / THREADS;
    const int gW = ((size_t)N * 4 + THREADS - 1) / THREADS;

    // -------- v2 layout --------
    const int NG    = (N + GWC - 1) >> SHC;     // col groups (128-wide)
    const int NGR   = (N + GWR - 1) >> SHR;     // row groups (2048-wide)
    const int NBLK2 = (E + CHUNK2 - 1) / CHUNK2;

    auto al = [](size_t v) { return (v + 255) & ~(size_t)255; };
    auto maxz = [](size_t a, size_t b) { return a > b ? a : b; };
    // region A1: A1 (E*4) later reused for h1 (64*N)
    size_t rA1 = al(maxz((size_t)E * 4, (size_t)64 * N));
    // region B1A: B1 (E*2) then A (E*4)
    size_t rB1A = al((size_t)E * 4);
    // region OFF: D2row + totR + basR (before), off (after)
    size_t offD2r  = 0;
    size_t offTotR = (size_t)NBLK2 * NGR;            // int index
    size_t offBasR = offTotR + NGR;
    size_t rOFF = al(maxz((size_t)N * 4, (offBasR + NGR + 1) * 4));
    // region DIS
    size_t rDIS = al((size_t)N * 4);
    // region D2C: D2col + totC + basC (before), s (after)
    size_t offTotC = (size_t)NBLK2 * NG;             // int index
    size_t offBasC = offTotC + NG;
    size_t rD2C = al(maxz((size_t)N * 4, (offBasC + NG + 1) * 4));
    size_t need_v2 = rA1 + rB1A + rOFF + rDIS + rD2C;

    // -------- round-6 layout --------
    const int NBIN = (N + BINW - 1) >> SH;
    const int NBLK = (E + CHUNK - 1) / CHUNK;
    size_t offB6 = 0;
    auto alloc6 = [&](size_t bytes) { size_t p = offB6; offB6 += al(bytes); return p; };
    size_t pA6    = alloc6((size_t)E * 4);
    size_t pCu8   = alloc6((size_t)E);
    size_t pOff6  = alloc6((size_t)N * 4);
    size_t pDis6  = alloc6((size_t)N * 4);
    size_t pS6    = alloc6((size_t)N * 4);
    size_t pTotC6 = alloc6((size_t)NBIN * 4);
    size_t pBasC6 = alloc6((size_t)(NBIN + 1) * 4);
    size_t pTotR6 = alloc6((size_t)NBIN * 4);
    size_t pBasR6 = alloc6((size_t)(NBIN + 1) * 4);
    size_t uni6 = maxz(maxz((size_t)2 * NBLK * NBIN * 4, (size_t)64 * N), (size_t)64 * SLOTU * 4);
    size_t pUni6 = alloc6(uni6);
    size_t need_6 = offB6;

    if (N <= MAXGC * GWC && NGR <= MAXGR && N <= (1 << 18) && ws_size >= need_v2) {
        char* base = (char*)d_ws;
        unsigned int* A1 = (unsigned int*)(base);                 // region A1
        float* h1        = (float*)(base);                        //   (after place2)
        unsigned short* B1 = (unsigned short*)(base + rA1);       // region B1A
        int* A             = (int*)(base + rA1);                  //   (after deg2)
        int* regOff = (int*)(base + rA1 + rB1A);
        int* D2r  = regOff + offD2r;
        int* totR = regOff + offTotR;
        int* basR = regOff + offBasR;
        int* off  = regOff;                                       //   (after place2)
        float* dis = (float*)(base + rA1 + rB1A + rOFF);
        int* regD2c = (int*)(base + rA1 + rB1A + rOFF + rDIS);
        int* D2c  = regD2c;
        int* totC = regD2c + offTotC;
        int* basC = regD2c + offBasC;
        float* s  = (float*)regD2c;                               //   (after place2/g2)

        int gABc = (int)(((size_t)NBLK2 * NG + THREADS - 1) / THREADS);
        int gABr = (int)(((size_t)NBLK2 * NGR + THREADS - 1) / THREADS);

        hist2_kernel<<<NBLK2, THREADS, 0, stream>>>(row, col, D2c, D2r, E, NG, NGR);
        scan_col_kernel<<<NG, THREADS, 0, stream>>>(D2c, totC, NBLK2, NG);
        scan_col_kernel<<<NGR, THREADS, 0, stream>>>(D2r, totR, NBLK2, NGR);
        scan_bins_kernel<<<1, 1024, 0, stream>>>(totC, basC, NG);
        scan_bins_kernel<<<1, 1024, 0, stream>>>(totR, basR, NGR);
        add_base_kernel<<<gABc, THREADS, 0, stream>>>(D2c, basC, NBLK2, NG);
        add_base_kernel<<<gABr, THREADS, 0, stream>>>(D2r, basR, NBLK2, NGR);
        scatter2_kernel<<<NBLK2, THREADS, 0, stream>>>(row, col, D2c, D2r, A1, B1, E, NG, NGR);
        deg2_kernel<<<NGR, THREADS, 0, stream>>>(B1, basR, dis, N);            // B1 dead after
        place2_kernel<<<NG, THREADS, 0, stream>>>(A1, basC, off, A, N);        // A1, D2*, bases dead after
        gather_dense1_w4<<<gW, THREADS, 0, stream>>>(off, A, dis, x, W1_0, W1_1, b1, h1, N, E);
        gather_dense2_w4<<<gW, THREADS, 0, stream>>>(off, A, dis, h1, W2_0, W2_1, b2, Wr, br, s, N, E);
        softmax_kernel<<<G, THREADS, 0, stream>>>(s, batch, out, N);
    } else if (N <= (1 << 18) && NBIN <= MAXBIN && ws_size >= need_6) {
        char* base = (char*)d_ws;
        unsigned int* A    = (unsigned int*)(base + pA6);
        unsigned char* Cu8 = (unsigned char*)(base + pCu8);
        int* off   = (int*)(base + pOff6);
        float* dis = (float*)(base + pDis6);
        float* s   = (float*)(base + pS6);
        int* totC  = (int*)(base + pTotC6);
        int* basC  = (int*)(base + pBasC6);
        int* totR  = (int*)(base + pTotR6);
        int* basR  = (int*)(base + pBasR6);
        int* Dcol  = (int*)(base + pUni6);
        int* Drow  = Dcol + (size_t)NBLK * NBIN;
        float* h1  = (float*)(base + pUni6);
        unsigned int* scratch = (unsigned int*)(base + pUni6);

        int gAB = (int)(((size_t)NBLK * NBIN + THREADS - 1) / THREADS);

        hist_kernel<<<NBLK, THREADS, 0, stream>>>(row, col, Dcol, Drow, E, NBIN);
        scan_col_kernel<<<NBIN, THREADS, 0, stream>>>(Dcol, totC, NBLK, NBIN);
        scan_col_kernel<<<NBIN, THREADS, 0, stream>>>(Drow, totR, NBLK, NBIN);
        scan_bins_kernel<<<1, 1024, 0, stream>>>(totC, basC, NBIN);
        scan_bins_kernel<<<1, 1024, 0, stream>>>(totR, basR, NBIN);
        add_base_kernel<<<gAB, THREADS, 0, stream>>>(Dcol, basC, NBLK, NBIN);
        add_base_kernel<<<gAB, THREADS, 0, stream>>>(Drow, basR, NBLK, NBIN);
        scatter_kernel<<<NBLK, THREADS, 0, stream>>>(row, col, Dcol, Drow, A, Cu8, E, NBIN);
        deg_bins_kernel<<<NBIN, THREADS, 0, stream>>>(Cu8, basR, dis, N);
        csr_place_kernel<<<NBIN, THREADS, 0, stream>>>(A, basC, off, scratch, N);
        gather_dense1_w4<<<gW, THREADS, 0, stream>>>(off, (const int*)A, dis, x, W1_0, W1_1, b1, h1, N, E);
        gather_dense2_w4<<<gW, THREADS, 0, stream>>>(off, (const int*)A, dis, h1, W2_0, W2_1, b2, Wr, br, s, N, E);
        softmax_kernel<<<G, THREADS, 0, stream>>>(s, batch, out, N);
    } else {
        int* deg_i = (int*)d_ws;
        int* cnt   = deg_i + N;
        int* fill  = cnt + N;
        int* off   = fill + N;
        int* bsum  = off + N;
        float* dis = (float*)(bsum + 1024);
        float* h1  = dis + N;
        float* s   = h1 + (size_t)16 * N;
        int* csr   = (int*)(s + N);

        hipMemsetAsync(deg_i, 0, sizeof(int) * (size_t)3 * N, stream);

        deg_cnt_kernel<<<gE, THREADS, 0, stream>>>(row, col, deg_i, cnt, E);
        dis_kernel_i<<<gN, THREADS, 0, stream>>>(deg_i, dis, N);
        scan1_kernel<<<gN, THREADS, 0, stream>>>(cnt, off, bsum, N);
        scan2_kernel<<<1, 1024, 0, stream>>>(bsum, gN);
        scan3_kernel<<<gN, THREADS, 0, stream>>>(off, bsum, N);
        fill_csr_kernel<<<gE, THREADS, 0, stream>>>(row, col, off, fill, csr, E);
        gather_dense1_w4<<<gW, THREADS, 0, stream>>>(off, csr, dis, x, W1_0, W1_1, b1, h1, N, E);
        gather_dense2_w4<<<gW, THREADS, 0, stream>>>(off, csr, dis, h1, W2_0, W2_1, b2, Wr, br, s, N, E);
        softmax_kernel<<<G, THREADS, 0, stream>>>(s, batch, out, N);
    }
}